// Round 11
// baseline (288.024 us; speedup 1.0000x reference)
//
#include <hip/hip_runtime.h>

// Problem constants (B, L, D, H) = (16, 512, 128, 8)
#define B_  16
#define L_  512
#define D_  128
#define H_  8
#define HD_ 1024   // H*D
#define NH_ 128    // H*B
#define M_  8192   // B*L

typedef unsigned short u16;
typedef __attribute__((ext_vector_type(8))) short s16x8;      // 8 bf16 = 4 VGPRs
typedef __attribute__((ext_vector_type(4))) float f32x4;      // MFMA accumulator
typedef __attribute__((ext_vector_type(4))) unsigned u32x4;   // 16B int vector (NT-capable)

// ---------- bf16 helpers (raw ushort representation) ----------
__device__ __forceinline__ float bf2f(u16 u) {
    union { unsigned u; float f; } x; x.u = ((unsigned)u) << 16; return x.f;
}
__device__ __forceinline__ u16 f2bf(float f) {
    unsigned u = __float_as_uint(f);
    return (u16)((u + 0x7FFFu + ((u >> 16) & 1u)) >> 16);   // RNE
}

// Load an 8-element bf16 fragment from a raw input that is either bf16
// (dt=1, direct 16B load) or fp32 (dt=0, 32B load + RNE convert).
// Produces bit-identical values to the old kprep-then-load path.
__device__ __forceinline__ s16x8 ldfrag8(const void* __restrict__ base,
                                         size_t off, int dt) {
    if (dt) {
        return *(const s16x8*)((const u16*)base + off);
    } else {
        const float* s = (const float*)base + off;
        f32x4 a = *(const f32x4*)s;
        f32x4 b = *(const f32x4*)(s + 4);
        u16 tmp[8] = {f2bf(a[0]), f2bf(a[1]), f2bf(a[2]), f2bf(a[3]),
                      f2bf(b[0]), f2bf(b[1]), f2bf(b[2]), f2bf(b[3])};
        return *(const s16x8*)tmp;
    }
}

// ---------------------------------------------------------------
// K0: dtype detect (content-based) — runs only if in_sizes is ambiguous.
// ---------------------------------------------------------------
__global__ void k0_detect(const unsigned int* __restrict__ pad,
                          const unsigned int* __restrict__ xw,
                          int* __restrict__ flags) {
    __shared__ int sMask, sCnt;
    if (threadIdx.x == 0) { sMask = 0; sCnt = 0; }
    __syncthreads();
    int bad = 0;
#pragma unroll
    for (int i = 0; i < 4; i++) {
        unsigned u = pad[threadIdx.x * 4 + i];
        bad |= (u > 1u) ? 1 : 0;
    }
    int cnt = 0;
#pragma unroll
    for (int i = 0; i < 16; i++) {
        unsigned w = xw[threadIdx.x * 16 + i];
        unsigned e = (w >> 7) & 0xFFu;
        cnt += (e >= 100u && e <= 131u) ? 1 : 0;
    }
    if (bad) atomicOr(&sMask, 1);
    atomicAdd(&sCnt, cnt);
    __syncthreads();
    if (threadIdx.x == 0) {
        flags[0] = (sCnt > 2048) ? 1 : 0;   // 1 => floats are bf16
        flags[1] = sMask;                   // 1 => mask is uint8
    }
}

// ---------------------------------------------------------------
// K1 mega: QKV projection with INLINE dtype conversion (x, W, b read
// raw — kprep-conv deleted) + mask-pack/colsum-zero as z=3 blocks
// (kprep-mask deleted).  grid (64 mt, 8 h, 4): z<3 = Q/K/V; z=3 = mask.
// mt on x => the 24 (h,z) blocks sharing one x-slice are stride-64 in
// linear id == same XCD => x read once per XCD then L2-hot.
// q,k head-major [n=h*16+bb][l][d]; v TRANSPOSED [n][d][l].
// ---------------------------------------------------------------
__global__ __launch_bounds__(256) void k1_proj(
    const void* __restrict__ x,
    const void* __restrict__ Wq, const void* __restrict__ Wk, const void* __restrict__ Wv,
    const void* __restrict__ bq, const void* __restrict__ bk, const void* __restrict__ bv,
    const void* __restrict__ pad, const int* __restrict__ flags,
    int dth, int dtm,
    u16* __restrict__ qb, u16* __restrict__ kb, u16* __restrict__ vtb,
    unsigned* __restrict__ mb, float* __restrict__ colsum) {
    if (blockIdx.z == 3) {
        // ---- mask-pack + colsum zero (512 blocks x 256 threads) ----
        int w = (blockIdx.y * 64 + blockIdx.x) * 256 + threadIdx.x;   // < 131072
        if (w < NH_ * L_) colsum[w] = 0.0f;
        const int m8 = (dtm >= 0) ? dtm : flags[1];
        unsigned m = 0;
        if (m8) {                                    // uint8 mask: 32 B = 2 x 16B
            const u32x4* p = (const u32x4*)pad + (size_t)w * 2;
            u32x4 a = __builtin_nontemporal_load(p);
            u32x4 c = __builtin_nontemporal_load(p + 1);
            unsigned ws[8] = {a[0], a[1], a[2], a[3], c[0], c[1], c[2], c[3]};
#pragma unroll
            for (int i = 0; i < 8; i++) {
                unsigned v = ws[i];
                m |= ((v & 0xFFu)        ? 1u : 0u) << (i * 4)
                   | ((v & 0xFF00u)     ? 1u : 0u) << (i * 4 + 1)
                   | ((v & 0xFF0000u)   ? 1u : 0u) << (i * 4 + 2)
                   | ((v & 0xFF000000u) ? 1u : 0u) << (i * 4 + 3);
            }
        } else {                                     // int32 mask: 128 B = 8 x 16B
            const u32x4* p = (const u32x4*)pad + (size_t)w * 8;
#pragma unroll
            for (int i = 0; i < 8; i++) {
                u32x4 v = __builtin_nontemporal_load(p + i);
                m |= (v[0] ? 1u : 0u) << (i * 4)
                   | (v[1] ? 1u : 0u) << (i * 4 + 1)
                   | (v[2] ? 1u : 0u) << (i * 4 + 2)
                   | (v[3] ? 1u : 0u) << (i * 4 + 3);
            }
        }
        mb[w] = m;
        return;
    }

    const int dt = (dth >= 0) ? dth : flags[0];
    const int h  = blockIdx.y;           // head (128 e per head)
    const int m0 = blockIdx.x * 128;
    const int z  = blockIdx.z;
    const void* W    = (z == 0) ? Wq : (z == 1) ? Wk : Wv;
    const void* bias = (z == 0) ? bq : (z == 1) ? bk : bv;

    const int lane = threadIdx.x & 63, wave = threadIdx.x >> 6;
    const int wr = wave >> 1, wc = wave & 1;
    const int mr = lane & 15, quad = lane >> 4;

    f32x4 acc[4][4];
#pragma unroll
    for (int i = 0; i < 4; i++)
#pragma unroll
        for (int j = 0; j < 4; j++) acc[i][j] = (f32x4){0.f, 0.f, 0.f, 0.f};

    // MFMA with inline-converted fragments (bit-identical to staged path)
    for (int k0 = 0; k0 < D_; k0 += 32) {
        s16x8 av[4], bvf[4];
#pragma unroll
        for (int i = 0; i < 4; i++)
            av[i] = ldfrag8(x, (size_t)(m0 + wr * 64 + i * 16 + mr) * D_ + k0 + quad * 8, dt);
#pragma unroll
        for (int j = 0; j < 4; j++)
            bvf[j] = ldfrag8(W, (size_t)(h * 128 + wc * 64 + j * 16 + mr) * D_ + k0 + quad * 8, dt);
#pragma unroll
        for (int i = 0; i < 4; i++)
#pragma unroll
            for (int j = 0; j < 4; j++)
                acc[i][j] = __builtin_amdgcn_mfma_f32_16x16x32_bf16(av[i], bvf[j], acc[i][j], 0, 0, 0);
    }

    __shared__ __align__(16) u16 T[128][144];
#pragma unroll
    for (int i = 0; i < 4; i++)
#pragma unroll
        for (int j = 0; j < 4; j++) {
            int col = wc * 64 + j * 16 + mr;
            float bv_ = dt ? bf2f(((const u16*)bias)[h * 128 + col])
                           : ((const float*)bias)[h * 128 + col];
#pragma unroll
            for (int r = 0; r < 4; r++)
                T[wr * 64 + i * 16 + quad * 4 + r][col] = f2bf(acc[i][j][r] + bv_);
        }
    __syncthreads();

    const int bb = m0 >> 9, l0 = m0 & 511;
    const int t = threadIdx.x;
    if (z < 2) {
        u16* out = z ? kb : qb;
        const int wv = t >> 6, l = t & 63;
        const int col = (l & 15) * 8;
#pragma unroll
        for (int p = 0; p < 8; p++) {
            int row = p * 16 + wv * 4 + (l >> 4);
            u16* dst = out + ((size_t)(h * B_ + bb) * L_ + l0 + row) * D_ + col;
            *(uint4*)dst = *(const uint4*)&T[row][col];
        }
    } else {
        int d = t >> 1, lc0 = (t & 1) * 64;
        u16* dst = vtb + ((size_t)(h * B_ + bb) * D_ + d) * L_ + l0 + lc0;
#pragma unroll
        for (int c = 0; c < 64; c += 8) {
            u16 tmp[8];
#pragma unroll
            for (int s = 0; s < 8; s++) tmp[s] = T[lc0 + c + s][d];
            *(uint4*)(dst + c) = *(const uint4*)tmp;
        }
    }
}

// ---------------------------------------------------------------
// K2: e-tile (128q x 128k) per block + pre-reduced colsum atomics.
// Round-8 proven geometry (49us) — k2 file CLOSED after 3-geometry
// sweep (19/32/46% occ => 59/49/57us; not occupancy- or BW-bound).
// grid (16, 128) XCD-swizzled: XCD x owns n in [16x,16x+16).
// ---------------------------------------------------------------
__global__ __launch_bounds__(256, 4) void k2_scores(
    const u16* __restrict__ qb, const u16* __restrict__ kb,
    const unsigned* __restrict__ mbits,
    u16* __restrict__ sb, float* __restrict__ colsum) {
    const int bid = blockIdx.y * 16 + blockIdx.x;       // 0..2047
    const int sw  = (bid & 7) * 256 + (bid >> 3);       // bijective XCD chunking
    const int n   = sw >> 4;
    const int qt  = (sw >> 2) & 3, kt = sw & 3;
    const int bb  = n & (B_ - 1);
    const int lane = threadIdx.x & 63, wave = threadIdx.x >> 6;
    const int wr = wave >> 1, wc = wave & 1;
    const int mr = lane & 15, quad = lane >> 4;
    const float rs = 0.08838834764831845f;   // 1/sqrt(128)

    __shared__ __align__(16) u16 T[128][136];
    __shared__ float CS[2][128];
    __shared__ unsigned MW[128][4];

    // stage this block's mask words: 128 q-rows x 4 dwords (2KB)
    {
        int t = threadIdx.x;
        int q = t >> 1, w2 = (t & 1) * 2;
        const unsigned* src = mbits + ((size_t)(bb << 9) + qt * 128 + q) * 16 + kt * 4 + w2;
        uint2 v = *(const uint2*)src;
        MW[q][w2] = v.x; MW[q][w2 + 1] = v.y;
    }

    f32x4 acc[4][4];
#pragma unroll
    for (int i = 0; i < 4; i++)
#pragma unroll
        for (int j = 0; j < 4; j++) acc[i][j] = (f32x4){0.f, 0.f, 0.f, 0.f};

    {
        const u16* A  = qb + ((size_t)n * L_ + qt * 128 + wr * 64) * D_;
        const u16* Bb = kb + ((size_t)n * L_ + kt * 128 + wc * 64) * D_;
        for (int k0 = 0; k0 < D_; k0 += 32) {
            s16x8 av[4], bv[4];
#pragma unroll
            for (int i = 0; i < 4; i++)
                av[i] = *(const s16x8*)(A + (size_t)(i * 16 + mr) * D_ + k0 + quad * 8);
#pragma unroll
            for (int j = 0; j < 4; j++)
                bv[j] = *(const s16x8*)(Bb + (size_t)(j * 16 + mr) * D_ + k0 + quad * 8);
#pragma unroll
            for (int i = 0; i < 4; i++)
#pragma unroll
                for (int j = 0; j < 4; j++)
                    acc[i][j] = __builtin_amdgcn_mfma_f32_16x16x32_bf16(av[i], bv[j], acc[i][j], 0, 0, 0);
        }
    }
    __syncthreads();   // MW visible (latency hidden under MFMA)

    float cs[4] = {0.f, 0.f, 0.f, 0.f};
#pragma unroll
    for (int j = 0; j < 4; j++) {
        const int wsel = wc * 2 + (j >> 1);
        const int bit  = ((j & 1) << 4) + mr;
#pragma unroll
        for (int i = 0; i < 4; i++)
#pragma unroll
            for (int r = 0; r < 4; r++) {
                int ql = wr * 64 + i * 16 + quad * 4 + r;
                unsigned w = MW[ql][wsel];
                float e = ((w >> bit) & 1u) ? 0.f : __expf(acc[i][j][r] * rs);
                cs[j] += e;
                T[ql][wc * 64 + j * 16 + mr] = f2bf(e);
            }
    }
    // reduce over the 4 quads (same column within the wave)
#pragma unroll
    for (int j = 0; j < 4; j++) {
        cs[j] += __shfl_xor(cs[j], 16);
        cs[j] += __shfl_xor(cs[j], 32);
    }
    if (quad == 0) {
#pragma unroll
        for (int j = 0; j < 4; j++) CS[wr][wc * 64 + j * 16 + mr] = cs[j];
    }
    __syncthreads();
    // coalesced e-store: 16 lanes cover one 256B row segment
    {
        int t = threadIdx.x;
        const int col = (t & 15) * 8;
        const int rb  = t >> 4;             // 0..15
#pragma unroll
        for (int p = 0; p < 8; p++) {
            int row = p * 16 + rb;
            u16* dst = sb + ((size_t)n * L_ + qt * 128 + row) * L_ + kt * 128 + col;
            *(uint4*)dst = *(const uint4*)&T[row][col];
        }
    }
    // one atomic per column per block (4 blocks contribute per column)
    if (threadIdx.x < 128)
        atomicAdd(&colsum[(size_t)n * L_ + kt * 128 + threadIdx.x],
                  CS[0][threadIdx.x] + CS[1][threadIdx.x]);
}

// ---------------------------------------------------------------
// K4: att[n,q,d] = sum_k (e[q,k]/colsum[k]) * vt'[d,k].
// 1/colsum folded into the A-fragment load.  grid (4,128) XCD-swizzled
// (XCD x owns n in [16x,16x+16) => vtb fetched once per XCD, reused 4x).
// Store: wave writes 1KB contiguous (4 adjacent 256B D-rows).
// ---------------------------------------------------------------
__global__ __launch_bounds__(256) void k4_av(
    const u16* __restrict__ sb, const u16* __restrict__ vtb,
    const float* __restrict__ colsum, u16* __restrict__ att) {
    const int bid = blockIdx.y * 4 + blockIdx.x;        // 0..511
    const int sw  = (bid & 7) * 64 + (bid >> 3);        // bijective XCD chunking
    const int n   = sw >> 2;
    const int q0  = (sw & 3) * 128;
    const int lane = threadIdx.x & 63, wave = threadIdx.x >> 6;
    const int wr = wave >> 1, wc = wave & 1;
    const int mr = lane & 15, quad = lane >> 4;

    f32x4 acc[4][4];
#pragma unroll
    for (int i = 0; i < 4; i++)
#pragma unroll
        for (int j = 0; j < 4; j++) acc[i][j] = (f32x4){0.f, 0.f, 0.f, 0.f};

    const u16* A   = sb  + ((size_t)n * L_ + q0 + wr * 64) * L_;
    const u16* Bb  = vtb + ((size_t)n * D_ + wc * 64) * L_;
    const float* cs = colsum + (size_t)n * L_;

    for (int k0 = 0; k0 < L_; k0 += 32) {
        const int kk = k0 + quad * 8;
        float lv[8];
        *(float4*)&lv[0] = *(const float4*)(cs + kk);
        *(float4*)&lv[4] = *(const float4*)(cs + kk + 4);
#pragma unroll
        for (int s = 0; s < 8; s++) lv[s] = __builtin_amdgcn_rcpf(lv[s]);

        s16x8 av[4], bv[4];
#pragma unroll
        for (int i = 0; i < 4; i++)
            av[i] = *(const s16x8*)(A + (size_t)(i * 16 + mr) * L_ + kk);
#pragma unroll
        for (int j = 0; j < 4; j++)
            bv[j] = *(const s16x8*)(Bb + (size_t)(j * 16 + mr) * L_ + kk);
        // scale e by 1/colsum[k] (per-k, pre-MFMA)
#pragma unroll
        for (int i = 0; i < 4; i++) {
            u16* u = (u16*)&av[i];
#pragma unroll
            for (int s = 0; s < 8; s++) u[s] = f2bf(bf2f(u[s]) * lv[s]);
        }
#pragma unroll
        for (int i = 0; i < 4; i++)
#pragma unroll
            for (int j = 0; j < 4; j++)
                acc[i][j] = __builtin_amdgcn_mfma_f32_16x16x32_bf16(av[i], bv[j], acc[i][j], 0, 0, 0);
    }

    __shared__ __align__(16) u16 T[128][136];
#pragma unroll
    for (int i = 0; i < 4; i++)
#pragma unroll
        for (int j = 0; j < 4; j++) {
            int col = wc * 64 + j * 16 + mr;
#pragma unroll
            for (int r = 0; r < 4; r++)
                T[wr * 64 + i * 16 + quad * 4 + r][col] = f2bf(acc[i][j][r]);
        }
    __syncthreads();
    {
        int t = threadIdx.x;
        const int wv = t >> 6, l = t & 63;
        const int col = (l & 15) * 8;
#pragma unroll
        for (int p = 0; p < 8; p++) {
            int row = p * 16 + wv * 4 + (l >> 4);
            u16* dst = att + ((size_t)n * L_ + q0 + row) * D_ + col;
            *(uint4*)dst = *(const uint4*)&T[row][col];
        }
    }
}

// ---------------------------------------------------------------
// K5: out = att_flat[8192][1024] @ Wo[128][1024]^T + bo.
// Wo/bo read RAW with inline conversion (Wo fp32 = 512KB, L2-resident).
// BM=32, BN=128, 4 waves (wave w: 32q x 32 cols, acc[2][2]), grid 256.
// ---------------------------------------------------------------
__global__ __launch_bounds__(256) void k5_out(
    const u16* __restrict__ att, const void* __restrict__ Wo,
    const void* __restrict__ bo, const int* __restrict__ flags, int dth,
    void* __restrict__ out) {
    const int dt = (dth >= 0) ? dth : flags[0];
    const int m0 = blockIdx.x * 32;
    const int lane = threadIdx.x & 63, wave = threadIdx.x >> 6;
    const int mr = lane & 15, quad = lane >> 4;

    f32x4 acc[2][2];
#pragma unroll
    for (int i = 0; i < 2; i++)
#pragma unroll
        for (int j = 0; j < 2; j++) acc[i][j] = (f32x4){0.f, 0.f, 0.f, 0.f};

    const u16* A = att + (size_t)m0 * HD_;
    for (int k0 = 0; k0 < HD_; k0 += 32) {
        s16x8 av[2], bv[2];
#pragma unroll
        for (int i = 0; i < 2; i++)
            av[i] = *(const s16x8*)(A + (size_t)(i * 16 + mr) * HD_ + k0 + quad * 8);
#pragma unroll
        for (int j = 0; j < 2; j++)
            bv[j] = ldfrag8(Wo, (size_t)(wave * 32 + j * 16 + mr) * HD_ + k0 + quad * 8, dt);
#pragma unroll
        for (int i = 0; i < 2; i++)
#pragma unroll
            for (int j = 0; j < 2; j++)
                acc[i][j] = __builtin_amdgcn_mfma_f32_16x16x32_bf16(av[i], bv[j], acc[i][j], 0, 0, 0);
    }

    __shared__ __align__(16) float Tf[32][132];
#pragma unroll
    for (int i = 0; i < 2; i++)
#pragma unroll
        for (int j = 0; j < 2; j++) {
            int col = wave * 32 + j * 16 + mr;
            float bv_ = dt ? bf2f(((const u16*)bo)[col]) : ((const float*)bo)[col];
#pragma unroll
            for (int r = 0; r < 4; r++)
                Tf[i * 16 + quad * 4 + r][col] = acc[i][j][r] + bv_;
        }
    __syncthreads();
    int t = threadIdx.x, row = t >> 3, cg = (t & 7) * 16;
    size_t base = (size_t)(m0 + row) * D_ + cg;
    if (dt) {
        u16* o = (u16*)out;
        u16 tmp[16];
#pragma unroll
        for (int s = 0; s < 16; s++) tmp[s] = f2bf(Tf[row][cg + s]);
        *(uint4*)(o + base)     = *(const uint4*)&tmp[0];
        *(uint4*)(o + base + 8) = *(const uint4*)&tmp[8];
    } else {
        float* o = (float*)out;
#pragma unroll
        for (int c = 0; c < 16; c += 4)
            *(float4*)(o + base + c) = *(const float4*)&Tf[row][cg + c];
    }
}

// ---------------------------------------------------------------
extern "C" void kernel_launch(void* const* d_in, const int* in_sizes, int n_in,
                              void* d_out, int out_size, void* d_ws, size_t ws_size,
                              hipStream_t stream) {
    (void)out_size; (void)ws_size;
    const void* x  = d_in[0];
    const void* Wq = d_in[1]; const void* bq = d_in[2];
    const void* Wk = d_in[3]; const void* bk = d_in[4];
    const void* Wv = d_in[5]; const void* bv = d_in[6];
    const void* Wo = d_in[7]; const void* bo = d_in[8];
    const void* pad = d_in[9];

    char* p = (char*)d_ws;
    auto alloc = [&](size_t bytes) { char* r = p; p += (bytes + 255) & ~(size_t)255; return r; };
    int*  flags = (int*)alloc(256);
    unsigned* mbits = (unsigned*)alloc(524288);
    float* colsum = (float*)alloc(262144);    // [128 n][512 k] fp32
    u16*  qb   = (u16*)alloc(16777216);
    u16*  kb   = (u16*)alloc(16777216);
    u16*  vtb  = (u16*)alloc(16777216);
    u16*  sb   = (u16*)alloc(67108864);
    u16*  att  = qb;   // alias: qb dead after k2; k4 writes disjoint q-rows

    // Host-side dtype detection — ONLY when in_sizes is provably in BYTES.
    // (Round-9 trap: pad's element count == pad's u8 byte size; x's element
    // count is distinct from both of x's byte sizes, so x proves the units.)
    int dth = -1, dtm = -1;
    if (in_sizes && n_in >= 10) {
        if      (in_sizes[0] == 4194304) dth = 0;   // bytes, fp32
        else if (in_sizes[0] == 2097152) dth = 1;   // bytes, bf16
        if (dth >= 0) {                              // units proven = bytes
            if      (in_sizes[9] == 16777216) dtm = 0;   // int32 mask
            else if (in_sizes[9] == 4194304)  dtm = 1;   // uint8 mask
        }
    }
    if (dth < 0 || dtm < 0) {
        dth = -1; dtm = -1;   // use k0's flags for both (consistent source)
        k0_detect<<<1, 256, 0, stream>>>((const unsigned*)pad, (const unsigned*)x, flags);
    }

    k1_proj<<<dim3(64, 8, 4), 256, 0, stream>>>(
        x, Wq, Wk, Wv, bq, bk, bv, pad, flags, dth, dtm,
        qb, kb, vtb, mbits, colsum);
    k2_scores<<<dim3(16, NH_), 256, 0, stream>>>(qb, kb, mbits, sb, colsum);
    k4_av<<<dim3(4, NH_), 256, 0, stream>>>(sb, vtb, colsum, att);
    k5_out<<<256, 256, 0, stream>>>(att, Wo, bo, flags, dth, d_out);
}

// Round 12
// 230.163 us; speedup vs baseline: 1.2514x; 1.2514x over previous
//
#include <hip/hip_runtime.h>

// Problem constants (B, L, D, H) = (16, 512, 128, 8)
#define B_  16
#define L_  512
#define D_  128
#define H_  8
#define HD_ 1024   // H*D
#define NH_ 128    // H*B
#define M_  8192   // B*L

typedef unsigned short u16;
typedef __attribute__((ext_vector_type(8))) short s16x8;      // 8 bf16 = 4 VGPRs
typedef __attribute__((ext_vector_type(4))) float f32x4;      // MFMA accumulator
typedef __attribute__((ext_vector_type(4))) unsigned u32x4;   // 16B int vector (NT-capable)

// ---------- bf16 helpers (raw ushort representation) ----------
__device__ __forceinline__ float bf2f(u16 u) {
    union { unsigned u; float f; } x; x.u = ((unsigned)u) << 16; return x.f;
}
__device__ __forceinline__ u16 f2bf(float f) {
    unsigned u = __float_as_uint(f);
    return (u16)((u + 0x7FFFu + ((u >> 16) & 1u)) >> 16);   // RNE
}

// ---------------------------------------------------------------
// K0: dtype detect (content-based) — runs only if in_sizes is ambiguous.
// ---------------------------------------------------------------
__global__ void k0_detect(const unsigned int* __restrict__ pad,
                          const unsigned int* __restrict__ xw,
                          int* __restrict__ flags) {
    __shared__ int sMask, sCnt;
    if (threadIdx.x == 0) { sMask = 0; sCnt = 0; }
    __syncthreads();
    int bad = 0;
#pragma unroll
    for (int i = 0; i < 4; i++) {
        unsigned u = pad[threadIdx.x * 4 + i];
        bad |= (u > 1u) ? 1 : 0;
    }
    int cnt = 0;
#pragma unroll
    for (int i = 0; i < 16; i++) {
        unsigned w = xw[threadIdx.x * 16 + i];
        unsigned e = (w >> 7) & 0xFFu;
        cnt += (e >= 100u && e <= 131u) ? 1 : 0;
    }
    if (bad) atomicOr(&sMask, 1);
    atomicAdd(&sCnt, cnt);
    __syncthreads();
    if (threadIdx.x == 0) {
        flags[0] = (sCnt > 2048) ? 1 : 0;   // 1 => floats are bf16
        flags[1] = sMask;                   // 1 => mask is uint8
    }
}

// ---------------------------------------------------------------
// Kprep: merged conv (blocks [0,770)) + mask-pack (blocks [770,1282)).
// Staged conversion is the PROVEN structure (round 11: inline conversion
// in k1 re-converts 24x and doubles fragment load bytes => +53us).
// dth/dtm: host-detected dtypes; -1 => read flags (k0 ran).
// Input reads NT (read-once).  STORES regular (round 7: NT stores on
// partial lines => 2x write amplification).
// ---------------------------------------------------------------
#define PREP_TOT 1576064
#define PREP_V   197008   // PREP_TOT / 8
#define PREP_CONV_BLOCKS 770
#define PREP_MASK_BLOCKS 512
__global__ __launch_bounds__(256) void kprep(
    const void* x, const void* Wq, const void* bq, const void* Wk, const void* bk,
    const void* Wv, const void* bv, const void* Wo, const void* bo,
    const void* __restrict__ pad, const int* __restrict__ flags,
    int dth, int dtm,
    u16* xb, u16* Wqb, u16* Wkb, u16* Wvb, u16* Wob,
    u16* bqb, u16* bkb, u16* bvb, u16* bob,
    unsigned* __restrict__ mb, float* __restrict__ colsum) {
    const int b = blockIdx.x;
    if (b < PREP_CONV_BLOCKS) {
        int gid = b * 256 + threadIdx.x;
        if (gid >= PREP_V) return;
        int e0 = gid * 8;
        const int dt = (dth >= 0) ? dth : flags[0];
        const void* src; u16* dst; int off;
        if      (e0 < 1048576) { src = x;  dst = xb;  off = e0; }
        else if (e0 < 1179648) { src = Wq; dst = Wqb; off = e0 - 1048576; }
        else if (e0 < 1310720) { src = Wk; dst = Wkb; off = e0 - 1179648; }
        else if (e0 < 1441792) { src = Wv; dst = Wvb; off = e0 - 1310720; }
        else if (e0 < 1572864) { src = Wo; dst = Wob; off = e0 - 1441792; }
        else if (e0 < 1573888) { src = bq; dst = bqb; off = e0 - 1572864; }
        else if (e0 < 1574912) { src = bk; dst = bkb; off = e0 - 1573888; }
        else if (e0 < 1575936) { src = bv; dst = bvb; off = e0 - 1574912; }
        else                   { src = bo; dst = bob; off = e0 - 1575936; }
        if (dt) {
            u32x4 v = __builtin_nontemporal_load((const u32x4*)((const u16*)src + off));
            *(u32x4*)(dst + off) = v;
        } else {
            const float* s = (const float*)src + off;
            f32x4 a = __builtin_nontemporal_load((const f32x4*)s);
            f32x4 c = __builtin_nontemporal_load((const f32x4*)(s + 4));
            u16 tmp[8] = {f2bf(a[0]), f2bf(a[1]), f2bf(a[2]), f2bf(a[3]),
                          f2bf(c[0]), f2bf(c[1]), f2bf(c[2]), f2bf(c[3])};
            *(u32x4*)(dst + off) = *(const u32x4*)tmp;
        }
    } else {
        int w = (b - PREP_CONV_BLOCKS) * 256 + threadIdx.x;   // < 131072
        if (w < NH_ * L_) colsum[w] = 0.0f;                   // 65536 floats
        const int m8 = (dtm >= 0) ? dtm : flags[1];
        unsigned m = 0;
        if (m8) {                                    // uint8 mask: 32 B = 2 x 16B
            const u32x4* p = (const u32x4*)pad + (size_t)w * 2;
            u32x4 a = __builtin_nontemporal_load(p);
            u32x4 c = __builtin_nontemporal_load(p + 1);
            unsigned ws[8] = {a[0], a[1], a[2], a[3], c[0], c[1], c[2], c[3]};
#pragma unroll
            for (int i = 0; i < 8; i++) {
                unsigned v = ws[i];
                m |= ((v & 0xFFu)        ? 1u : 0u) << (i * 4)
                   | ((v & 0xFF00u)     ? 1u : 0u) << (i * 4 + 1)
                   | ((v & 0xFF0000u)   ? 1u : 0u) << (i * 4 + 2)
                   | ((v & 0xFF000000u) ? 1u : 0u) << (i * 4 + 3);
            }
        } else {                                     // int32 mask: 128 B = 8 x 16B
            const u32x4* p = (const u32x4*)pad + (size_t)w * 8;
#pragma unroll
            for (int i = 0; i < 8; i++) {
                u32x4 v = __builtin_nontemporal_load(p + i);
                m |= (v[0] ? 1u : 0u) << (i * 4)
                   | (v[1] ? 1u : 0u) << (i * 4 + 1)
                   | (v[2] ? 1u : 0u) << (i * 4 + 2)
                   | (v[3] ? 1u : 0u) << (i * 4 + 3);
            }
        }
        mb[w] = m;
    }
}

// ---------------------------------------------------------------
// K1: QKV projection via MFMA.  y = x @ W^T + b.
// q,k written head-major [n=h*16+bb][l][d]; v written TRANSPOSED [n][d][l].
// grid (64 m-tiles, 8 heads, 3): m-tile on x so the 24 (h,z) blocks that
// share one x-tile are stride-64 in linear id == same XCD (round-5 proven).
// q/k store: 16 lanes per 256B row, 4 contiguous rows per wave (1KB).
// ---------------------------------------------------------------
__global__ __launch_bounds__(256) void k1_proj(
    const u16* __restrict__ xb,
    const u16* __restrict__ Wqb, const u16* __restrict__ Wkb, const u16* __restrict__ Wvb,
    const u16* __restrict__ bqb, const u16* __restrict__ bkb, const u16* __restrict__ bvb,
    u16* __restrict__ qb, u16* __restrict__ kb, u16* __restrict__ vtb) {
    const int h  = blockIdx.y;           // e-tile == head (128 e per head)
    const int m0 = blockIdx.x * 128;
    const int z  = blockIdx.z;
    const u16* W    = (z == 0) ? Wqb : (z == 1) ? Wkb : Wvb;
    const u16* bias = (z == 0) ? bqb : (z == 1) ? bkb : bvb;

    const int lane = threadIdx.x & 63, wave = threadIdx.x >> 6;
    const int wr = wave >> 1, wc = wave & 1;
    const int mr = lane & 15, quad = lane >> 4;

    f32x4 acc[4][4];
#pragma unroll
    for (int i = 0; i < 4; i++)
#pragma unroll
        for (int j = 0; j < 4; j++) acc[i][j] = (f32x4){0.f, 0.f, 0.f, 0.f};

    {
        const u16* A  = xb + (size_t)(m0 + wr * 64) * D_;
        const u16* Bb = W + (size_t)(h * 128 + wc * 64) * D_;
        for (int k0 = 0; k0 < D_; k0 += 32) {
            s16x8 av[4], bv[4];
#pragma unroll
            for (int i = 0; i < 4; i++)
                av[i] = *(const s16x8*)(A + (size_t)(i * 16 + mr) * D_ + k0 + quad * 8);
#pragma unroll
            for (int j = 0; j < 4; j++)
                bv[j] = *(const s16x8*)(Bb + (size_t)(j * 16 + mr) * D_ + k0 + quad * 8);
#pragma unroll
            for (int i = 0; i < 4; i++)
#pragma unroll
                for (int j = 0; j < 4; j++)
                    acc[i][j] = __builtin_amdgcn_mfma_f32_16x16x32_bf16(av[i], bv[j], acc[i][j], 0, 0, 0);
        }
    }

    __shared__ __align__(16) u16 T[128][144];
#pragma unroll
    for (int i = 0; i < 4; i++)
#pragma unroll
        for (int j = 0; j < 4; j++) {
            int col = wc * 64 + j * 16 + mr;
            float bv_ = bf2f(bias[h * 128 + col]);
#pragma unroll
            for (int r = 0; r < 4; r++)
                T[wr * 64 + i * 16 + quad * 4 + r][col] = f2bf(acc[i][j][r] + bv_);
        }
    __syncthreads();

    const int bb = m0 >> 9, l0 = m0 & 511;
    const int t = threadIdx.x;
    if (z < 2) {
        u16* out = z ? kb : qb;
        const int wv = t >> 6, l = t & 63;
        const int col = (l & 15) * 8;
#pragma unroll
        for (int p = 0; p < 8; p++) {
            int row = p * 16 + wv * 4 + (l >> 4);
            u16* dst = out + ((size_t)(h * B_ + bb) * L_ + l0 + row) * D_ + col;
            *(uint4*)dst = *(const uint4*)&T[row][col];
        }
    } else {
        int d = t >> 1, lc0 = (t & 1) * 64;
        u16* dst = vtb + ((size_t)(h * B_ + bb) * D_ + d) * L_ + l0 + lc0;
#pragma unroll
        for (int c = 0; c < 64; c += 8) {
            u16 tmp[8];
#pragma unroll
            for (int s = 0; s < 8; s++) tmp[s] = T[lc0 + c + s][d];
            *(uint4*)(dst + c) = *(const uint4*)tmp;
        }
    }
}

// ---------------------------------------------------------------
// K2: e-tile (128q x 128k) per block + pre-reduced colsum atomics.
// Round-8 proven geometry (49us) — k2 file CLOSED after 3-geometry
// sweep (19/32/46% occ => 59/49/57us; not occupancy- or BW-bound).
// grid (16, 128) XCD-swizzled: XCD x owns n in [16x,16x+16).
// ---------------------------------------------------------------
__global__ __launch_bounds__(256, 4) void k2_scores(
    const u16* __restrict__ qb, const u16* __restrict__ kb,
    const unsigned* __restrict__ mbits,
    u16* __restrict__ sb, float* __restrict__ colsum) {
    const int bid = blockIdx.y * 16 + blockIdx.x;       // 0..2047
    const int sw  = (bid & 7) * 256 + (bid >> 3);       // bijective XCD chunking
    const int n   = sw >> 4;
    const int qt  = (sw >> 2) & 3, kt = sw & 3;
    const int bb  = n & (B_ - 1);
    const int lane = threadIdx.x & 63, wave = threadIdx.x >> 6;
    const int wr = wave >> 1, wc = wave & 1;
    const int mr = lane & 15, quad = lane >> 4;
    const float rs = 0.08838834764831845f;   // 1/sqrt(128)

    __shared__ __align__(16) u16 T[128][136];
    __shared__ float CS[2][128];
    __shared__ unsigned MW[128][4];

    // stage this block's mask words: 128 q-rows x 4 dwords (2KB)
    {
        int t = threadIdx.x;
        int q = t >> 1, w2 = (t & 1) * 2;
        const unsigned* src = mbits + ((size_t)(bb << 9) + qt * 128 + q) * 16 + kt * 4 + w2;
        uint2 v = *(const uint2*)src;
        MW[q][w2] = v.x; MW[q][w2 + 1] = v.y;
    }

    f32x4 acc[4][4];
#pragma unroll
    for (int i = 0; i < 4; i++)
#pragma unroll
        for (int j = 0; j < 4; j++) acc[i][j] = (f32x4){0.f, 0.f, 0.f, 0.f};

    {
        const u16* A  = qb + ((size_t)n * L_ + qt * 128 + wr * 64) * D_;
        const u16* Bb = kb + ((size_t)n * L_ + kt * 128 + wc * 64) * D_;
        for (int k0 = 0; k0 < D_; k0 += 32) {
            s16x8 av[4], bv[4];
#pragma unroll
            for (int i = 0; i < 4; i++)
                av[i] = *(const s16x8*)(A + (size_t)(i * 16 + mr) * D_ + k0 + quad * 8);
#pragma unroll
            for (int j = 0; j < 4; j++)
                bv[j] = *(const s16x8*)(Bb + (size_t)(j * 16 + mr) * D_ + k0 + quad * 8);
#pragma unroll
            for (int i = 0; i < 4; i++)
#pragma unroll
                for (int j = 0; j < 4; j++)
                    acc[i][j] = __builtin_amdgcn_mfma_f32_16x16x32_bf16(av[i], bv[j], acc[i][j], 0, 0, 0);
        }
    }
    __syncthreads();   // MW visible (latency hidden under MFMA)

    float cs[4] = {0.f, 0.f, 0.f, 0.f};
#pragma unroll
    for (int j = 0; j < 4; j++) {
        const int wsel = wc * 2 + (j >> 1);
        const int bit  = ((j & 1) << 4) + mr;
#pragma unroll
        for (int i = 0; i < 4; i++)
#pragma unroll
            for (int r = 0; r < 4; r++) {
                int ql = wr * 64 + i * 16 + quad * 4 + r;
                unsigned w = MW[ql][wsel];
                float e = ((w >> bit) & 1u) ? 0.f : __expf(acc[i][j][r] * rs);
                cs[j] += e;
                T[ql][wc * 64 + j * 16 + mr] = f2bf(e);
            }
    }
    // reduce over the 4 quads (same column within the wave)
#pragma unroll
    for (int j = 0; j < 4; j++) {
        cs[j] += __shfl_xor(cs[j], 16);
        cs[j] += __shfl_xor(cs[j], 32);
    }
    if (quad == 0) {
#pragma unroll
        for (int j = 0; j < 4; j++) CS[wr][wc * 64 + j * 16 + mr] = cs[j];
    }
    __syncthreads();
    // coalesced e-store: 16 lanes cover one 256B row segment
    {
        int t = threadIdx.x;
        const int col = (t & 15) * 8;
        const int rb  = t >> 4;             // 0..15
#pragma unroll
        for (int p = 0; p < 8; p++) {
            int row = p * 16 + rb;
            u16* dst = sb + ((size_t)n * L_ + qt * 128 + row) * L_ + kt * 128 + col;
            *(uint4*)dst = *(const uint4*)&T[row][col];
        }
    }
    // one atomic per column per block (4 blocks contribute per column)
    if (threadIdx.x < 128)
        atomicAdd(&colsum[(size_t)n * L_ + kt * 128 + threadIdx.x],
                  CS[0][threadIdx.x] + CS[1][threadIdx.x]);
}

// ---------------------------------------------------------------
// K4: att[n,q,d] = sum_k (e[q,k]/colsum[k]) * vt'[d,k].
// 1/colsum folded into the A-fragment load.  grid (4,128) XCD-swizzled
// (XCD x owns n in [16x,16x+16) => vtb fetched once per XCD, reused 4x).
// Store: wave writes 1KB contiguous (4 adjacent 256B D-rows).
// ---------------------------------------------------------------
__global__ __launch_bounds__(256) void k4_av(
    const u16* __restrict__ sb, const u16* __restrict__ vtb,
    const float* __restrict__ colsum, u16* __restrict__ att) {
    const int bid = blockIdx.y * 4 + blockIdx.x;        // 0..511
    const int sw  = (bid & 7) * 64 + (bid >> 3);        // bijective XCD chunking
    const int n   = sw >> 2;
    const int q0  = (sw & 3) * 128;
    const int lane = threadIdx.x & 63, wave = threadIdx.x >> 6;
    const int wr = wave >> 1, wc = wave & 1;
    const int mr = lane & 15, quad = lane >> 4;

    f32x4 acc[4][4];
#pragma unroll
    for (int i = 0; i < 4; i++)
#pragma unroll
        for (int j = 0; j < 4; j++) acc[i][j] = (f32x4){0.f, 0.f, 0.f, 0.f};

    const u16* A   = sb  + ((size_t)n * L_ + q0 + wr * 64) * L_;
    const u16* Bb  = vtb + ((size_t)n * D_ + wc * 64) * L_;
    const float* cs = colsum + (size_t)n * L_;

    for (int k0 = 0; k0 < L_; k0 += 32) {
        const int kk = k0 + quad * 8;
        float lv[8];
        *(float4*)&lv[0] = *(const float4*)(cs + kk);
        *(float4*)&lv[4] = *(const float4*)(cs + kk + 4);
#pragma unroll
        for (int s = 0; s < 8; s++) lv[s] = __builtin_amdgcn_rcpf(lv[s]);

        s16x8 av[4], bv[4];
#pragma unroll
        for (int i = 0; i < 4; i++)
            av[i] = *(const s16x8*)(A + (size_t)(i * 16 + mr) * L_ + kk);
#pragma unroll
        for (int j = 0; j < 4; j++)
            bv[j] = *(const s16x8*)(Bb + (size_t)(j * 16 + mr) * L_ + kk);
        // scale e by 1/colsum[k] (per-k, pre-MFMA)
#pragma unroll
        for (int i = 0; i < 4; i++) {
            u16* u = (u16*)&av[i];
#pragma unroll
            for (int s = 0; s < 8; s++) u[s] = f2bf(bf2f(u[s]) * lv[s]);
        }
#pragma unroll
        for (int i = 0; i < 4; i++)
#pragma unroll
            for (int j = 0; j < 4; j++)
                acc[i][j] = __builtin_amdgcn_mfma_f32_16x16x32_bf16(av[i], bv[j], acc[i][j], 0, 0, 0);
    }

    __shared__ __align__(16) u16 T[128][136];
#pragma unroll
    for (int i = 0; i < 4; i++)
#pragma unroll
        for (int j = 0; j < 4; j++) {
            int col = wc * 64 + j * 16 + mr;
#pragma unroll
            for (int r = 0; r < 4; r++)
                T[wr * 64 + i * 16 + quad * 4 + r][col] = f2bf(acc[i][j][r]);
        }
    __syncthreads();
    {
        int t = threadIdx.x;
        const int wv = t >> 6, l = t & 63;
        const int col = (l & 15) * 8;
#pragma unroll
        for (int p = 0; p < 8; p++) {
            int row = p * 16 + wv * 4 + (l >> 4);
            u16* dst = att + ((size_t)n * L_ + q0 + row) * D_ + col;
            *(uint4*)dst = *(const uint4*)&T[row][col];
        }
    }
}

// ---------------------------------------------------------------
// K5: out = att_flat[8192][1024] @ Wo[128][1024]^T + bo.
// BM=32, BN=128, 4 waves (wave w: 32q x 32 cols, acc[2][2]), grid 256.
// XCD-swizzled to match k4's att placement: block sw reads att flat
// rows [32sw,32sw+32) = n=sw/2, which k4 wrote on XCD sw/32 = bid&7
// => att read L2-hot instead of from HBM.  dth: host dtype; -1 => flags.
// ---------------------------------------------------------------
__global__ __launch_bounds__(256) void k5_out(
    const u16* __restrict__ att, const u16* __restrict__ Wob,
    const u16* __restrict__ bob, const int* __restrict__ flags, int dth,
    void* __restrict__ out) {
    const int dt = (dth >= 0) ? dth : flags[0];
    const int bid = blockIdx.x;                          // 0..255
    const int sw  = (bid & 7) * 32 + (bid >> 3);         // bijective, XCD-aligned
    const int m0 = sw * 32;
    const int lane = threadIdx.x & 63, wave = threadIdx.x >> 6;
    const int mr = lane & 15, quad = lane >> 4;

    f32x4 acc[2][2];
#pragma unroll
    for (int i = 0; i < 2; i++)
#pragma unroll
        for (int j = 0; j < 2; j++) acc[i][j] = (f32x4){0.f, 0.f, 0.f, 0.f};

    const u16* A  = att + (size_t)m0 * HD_;
    const u16* Bw = Wob + (size_t)(wave * 32) * HD_;
    for (int k0 = 0; k0 < HD_; k0 += 32) {
        s16x8 av[2], bv[2];
#pragma unroll
        for (int i = 0; i < 2; i++)
            av[i] = *(const s16x8*)(A + (size_t)(i * 16 + mr) * HD_ + k0 + quad * 8);
#pragma unroll
        for (int j = 0; j < 2; j++)
            bv[j] = *(const s16x8*)(Bw + (size_t)(j * 16 + mr) * HD_ + k0 + quad * 8);
#pragma unroll
        for (int i = 0; i < 2; i++)
#pragma unroll
            for (int j = 0; j < 2; j++)
                acc[i][j] = __builtin_amdgcn_mfma_f32_16x16x32_bf16(av[i], bv[j], acc[i][j], 0, 0, 0);
    }

    __shared__ __align__(16) float Tf[32][132];
#pragma unroll
    for (int i = 0; i < 2; i++)
#pragma unroll
        for (int j = 0; j < 2; j++) {
            int col = wave * 32 + j * 16 + mr;
            float bv_ = bf2f(bob[col]);
#pragma unroll
            for (int r = 0; r < 4; r++)
                Tf[i * 16 + quad * 4 + r][col] = acc[i][j][r] + bv_;
        }
    __syncthreads();
    int t = threadIdx.x, row = t >> 3, cg = (t & 7) * 16;
    size_t base = (size_t)(m0 + row) * D_ + cg;
    if (dt) {
        u16* o = (u16*)out;
        u16 tmp[16];
#pragma unroll
        for (int s = 0; s < 16; s++) tmp[s] = f2bf(Tf[row][cg + s]);
        *(uint4*)(o + base)     = *(const uint4*)&tmp[0];
        *(uint4*)(o + base + 8) = *(const uint4*)&tmp[8];
    } else {
        float* o = (float*)out;
#pragma unroll
        for (int c = 0; c < 16; c += 4)
            *(float4*)(o + base + c) = *(const float4*)&Tf[row][cg + c];
    }
}

// ---------------------------------------------------------------
extern "C" void kernel_launch(void* const* d_in, const int* in_sizes, int n_in,
                              void* d_out, int out_size, void* d_ws, size_t ws_size,
                              hipStream_t stream) {
    (void)out_size; (void)ws_size;
    const void* x  = d_in[0];
    const void* Wq = d_in[1]; const void* bq = d_in[2];
    const void* Wk = d_in[3]; const void* bk = d_in[4];
    const void* Wv = d_in[5]; const void* bv = d_in[6];
    const void* Wo = d_in[7]; const void* bo = d_in[8];
    const void* pad = d_in[9];

    char* p = (char*)d_ws;
    auto alloc = [&](size_t bytes) { char* r = p; p += (bytes + 255) & ~(size_t)255; return r; };
    int*  flags = (int*)alloc(256);
    u16*  xb   = (u16*)alloc(2097152);
    u16*  Wqb  = (u16*)alloc(262144);
    u16*  Wkb  = (u16*)alloc(262144);
    u16*  Wvb  = (u16*)alloc(262144);
    u16*  Wob  = (u16*)alloc(262144);
    u16*  bqb  = (u16*)alloc(2048);
    u16*  bkb  = (u16*)alloc(2048);
    u16*  bvb  = (u16*)alloc(2048);
    u16*  bob  = (u16*)alloc(256);
    unsigned* mbits = (unsigned*)alloc(524288);
    float* colsum = (float*)alloc(262144);    // [128 n][512 k] fp32
    u16*  qb   = (u16*)alloc(16777216);
    u16*  kb   = (u16*)alloc(16777216);
    u16*  vtb  = (u16*)alloc(16777216);
    u16*  sb   = (u16*)alloc(67108864);
    u16*  att  = qb;   // alias: qb dead after k2; k4 writes disjoint q-rows

    // Host-side dtype detection — ONLY when in_sizes is provably in BYTES.
    // (Round-9 trap: pad's element count == pad's u8 byte size; x's element
    // count is distinct from both of x's byte sizes, so x proves the units.)
    int dth = -1, dtm = -1;
    if (in_sizes && n_in >= 10) {
        if      (in_sizes[0] == 4194304) dth = 0;   // bytes, fp32
        else if (in_sizes[0] == 2097152) dth = 1;   // bytes, bf16
        if (dth >= 0) {                              // units proven = bytes
            if      (in_sizes[9] == 16777216) dtm = 0;   // int32 mask
            else if (in_sizes[9] == 4194304)  dtm = 1;   // uint8 mask
        }
    }
    if (dth < 0 || dtm < 0) {
        dth = -1; dtm = -1;   // use k0's flags for both (consistent source)
        k0_detect<<<1, 256, 0, stream>>>((const unsigned*)pad, (const unsigned*)x, flags);
    }

    kprep<<<PREP_CONV_BLOCKS + PREP_MASK_BLOCKS, 256, 0, stream>>>(
        x, Wq, bq, Wk, bk, Wv, bv, Wo, bo, pad, flags, dth, dtm,
        xb, Wqb, Wkb, Wvb, Wob, bqb, bkb, bvb, bob, mbits, colsum);
    k1_proj<<<dim3(64, 8, 3), 256, 0, stream>>>(
        xb, Wqb, Wkb, Wvb, bqb, bkb, bvb, qb, kb, vtb);
    k2_scores<<<dim3(16, NH_), 256, 0, stream>>>(qb, kb, mbits, sb, colsum);
    k4_av<<<dim3(4, NH_), 256, 0, stream>>>(sb, vtb, colsum, att);
    k5_out<<<256, 256, 0, stream>>>(att, Wob, bob, flags, dth, d_out);
}